// Round 8
// baseline (462.861 us; speedup 1.0000x reference)
//
#include <hip/hip_runtime.h>
#include <cstddef>

#define NN 50000
#define NE 400000
#define NH 4
#define NC 121
#define MAXSLOT 600000   // NE + 4*NN upper bound on padded CSR slots

typedef __attribute__((ext_vector_type(8))) short short8;
typedef __attribute__((ext_vector_type(4))) float f32x4;

// fp32 -> bf16 round-to-nearest-even
static __device__ __forceinline__ unsigned short f2bf(float f) {
    unsigned u = __float_as_uint(f);
    u += 0x7fffu + ((u >> 16) & 1u);
    return (unsigned short)(u >> 16);
}
static __device__ __forceinline__ float bf2f(unsigned short u) {
    return __uint_as_float(((unsigned)u) << 16);
}

// ================= cast kernels =================
__global__ __launch_bounds__(256) void cast_x(const float* __restrict__ in,
                                              unsigned short* __restrict__ out, int n4) {
    int i = blockIdx.x * blockDim.x + threadIdx.x;
    if (i >= n4) return;
    float4 v = *(const float4*)&in[i * 4];
    ushort4 o;
    o.x = f2bf(v.x); o.y = f2bf(v.y); o.z = f2bf(v.z); o.w = f2bf(v.w);
    *(ushort4*)&out[i * 4] = o;
}

__global__ __launch_bounds__(256) void cast_BT(const float* __restrict__ B,
                                               unsigned short* __restrict__ BT,
                                               int N, int Npad) {
    int i = blockIdx.x * blockDim.x + threadIdx.x;
    if (i >= Npad * 256) return;
    int n = i >> 8, k = i & 255;
    float v = (n < N) ? B[(size_t)k * N + n] : 0.f;
    BT[i] = f2bf(v);
}

// W3[256][484] -> BTcat[128][1024] bf16: BTcat[c][h*256+k] = 0.25*W3[k][h*121+c]
__global__ __launch_bounds__(256) void cast_BTcat(const float* __restrict__ W3,
                                                  unsigned short* __restrict__ BT) {
    int i = blockIdx.x * blockDim.x + threadIdx.x;
    if (i >= 128 * 1024) return;
    int c = i >> 10, kk = i & 1023;
    int h = kk >> 8, k = kk & 255;
    float v = (c < NC) ? 0.25f * W3[(size_t)k * 484 + h * NC + c] : 0.f;
    BT[i] = f2bf(v);
}

// wl3[h*256+k] = sum_d W3[k][h*121+d]*al3[h][d]; wr3 likewise
__global__ __launch_bounds__(256) void wvec3_k(const float* __restrict__ W3,
                                               const float* __restrict__ al3,
                                               const float* __restrict__ ar3,
                                               float* __restrict__ wl3,
                                               float* __restrict__ wr3) {
    int i = blockIdx.x * blockDim.x + threadIdx.x;
    if (i >= 2048) return;
    int j = i & 1023;
    int h = j >> 8, k = j & 255;
    const float* a = (i < 1024) ? al3 : ar3;
    const float* wrow = W3 + (size_t)k * 484 + h * NC;
    const float* arow = a + h * NC;
    float s = 0.f;
    for (int d = 0; d < NC; ++d) s += wrow[d] * arow[d];
    if (i < 1024) wl3[j] = s; else wr3[j] = s;
}

// ================= MFMA GEMM with optional fused attention-logit epilogue ==========
__global__ __launch_bounds__(256) void gemm_bf16(const unsigned short* __restrict__ A,
                                                 const unsigned short* __restrict__ BT,
                                                 float* __restrict__ Cf,
                                                 unsigned short* __restrict__ Cb,
                                                 const float* __restrict__ al,
                                                 const float* __restrict__ ar,
                                                 float* __restrict__ el,
                                                 float* __restrict__ er,
                                                 int M, int Nout, int K) {
    __shared__ __align__(16) unsigned short Alds[128 * 32];
    __shared__ __align__(16) unsigned short Blds[128 * 32];
    const int tid = threadIdx.x;
    const int wave = tid >> 6;
    const int lane = tid & 63;
    const int quad = lane >> 4;
    const int ml = lane & 15;
    const int m0 = blockIdx.x * 128;
    const int n0 = blockIdx.y * 128;
    const int wm0 = (wave >> 1) * 64;
    const int wn0 = (wave & 1) * 64;
    const int r = tid >> 2;
    const int c8 = (tid & 3) * 8;

    f32x4 acc[4][4] = {};

    for (int k0 = 0; k0 < K; k0 += 32) {
        #pragma unroll
        for (int p = 0; p < 2; ++p) {
            int rr = r + p * 64;
            int m = m0 + rr;
            uint4 va = make_uint4(0u, 0u, 0u, 0u);
            if (m < M) va = *(const uint4*)&A[(size_t)m * K + k0 + c8];
            *(uint4*)&Alds[rr * 32 + c8] = va;
            int n = n0 + rr;
            uint4 vb = *(const uint4*)&BT[(size_t)n * K + k0 + c8];
            *(uint4*)&Blds[rr * 32 + c8] = vb;
        }
        __syncthreads();

        short8 af[4], bf[4];
        #pragma unroll
        for (int i = 0; i < 4; ++i)
            af[i] = *(const short8*)&Alds[(wm0 + i * 16 + ml) * 32 + quad * 8];
        #pragma unroll
        for (int j = 0; j < 4; ++j)
            bf[j] = *(const short8*)&Blds[(wn0 + j * 16 + ml) * 32 + quad * 8];
        #pragma unroll
        for (int i = 0; i < 4; ++i)
            #pragma unroll
            for (int j = 0; j < 4; ++j)
                acc[i][j] = __builtin_amdgcn_mfma_f32_16x16x32_bf16(af[i], bf[j], acc[i][j], 0, 0, 0);
        __syncthreads();
    }

    // C/D layout: col = lane&15, row = quad*4 + reg
    #pragma unroll
    for (int i = 0; i < 4; ++i) {
        #pragma unroll
        for (int reg = 0; reg < 4; ++reg) {
            int m = m0 + wm0 + i * 16 + quad * 4 + reg;
            if (m >= M) continue;
            #pragma unroll
            for (int j = 0; j < 4; ++j) {
                int n = n0 + wn0 + j * 16 + ml;
                if (n < Nout) {
                    if (Cb) Cb[(size_t)m * Nout + n] = f2bf(acc[i][j][reg]);
                    else    Cf[(size_t)m * Nout + n] = acc[i][j][reg];
                }
            }
        }
    }

    // ---- fused attention logits (Nout==256 path only): wave's 64 cols = one head ----
    if (el) {
        int head = (n0 + wn0) >> 6;
        float alv[4], arv[4];
        #pragma unroll
        for (int j = 0; j < 4; ++j) {
            alv[j] = al[head * 64 + j * 16 + ml];
            arv[j] = ar[head * 64 + j * 16 + ml];
        }
        #pragma unroll
        for (int i = 0; i < 4; ++i) {
            #pragma unroll
            for (int reg = 0; reg < 4; ++reg) {
                float sl = 0.f, sr = 0.f;
                #pragma unroll
                for (int j = 0; j < 4; ++j) {
                    float v = acc[i][j][reg];
                    sl += v * alv[j];
                    sr += v * arv[j];
                }
                #pragma unroll
                for (int off = 1; off < 16; off <<= 1) {
                    sl += __shfl_xor(sl, off);
                    sr += __shfl_xor(sr, off);
                }
                int m = m0 + wm0 + i * 16 + quad * 4 + reg;
                if (ml == 0 && m < M) {
                    el[m * 4 + head] = sl;
                    er[m * 4 + head] = sr;
                }
            }
        }
    }
}

// ================= layer-3 logits =================
__global__ __launch_bounds__(256) void elr3_k(const unsigned short* __restrict__ x,
                                              const float* __restrict__ wl3,
                                              const float* __restrict__ wr3,
                                              float* __restrict__ el,
                                              float* __restrict__ er) {
    int wid = (blockIdx.x * blockDim.x + threadIdx.x) >> 6;
    int lane = threadIdx.x & 63;
    if (wid >= NN) return;
    ushort4 xv = *(const ushort4*)&x[(size_t)wid * 256 + lane * 4];
    float f[4] = {bf2f(xv.x), bf2f(xv.y), bf2f(xv.z), bf2f(xv.w)};
    float sl[4] = {}, sr[4] = {};
    #pragma unroll
    for (int h = 0; h < 4; ++h) {
        float4 a4 = *(const float4*)&wl3[h * 256 + lane * 4];
        float4 r4 = *(const float4*)&wr3[h * 256 + lane * 4];
        sl[h] = f[0] * a4.x + f[1] * a4.y + f[2] * a4.z + f[3] * a4.w;
        sr[h] = f[0] * r4.x + f[1] * r4.y + f[2] * r4.z + f[3] * r4.w;
    }
    #pragma unroll
    for (int off = 32; off; off >>= 1) {
        #pragma unroll
        for (int h = 0; h < 4; ++h) {
            sl[h] += __shfl_xor(sl[h], off);
            sr[h] += __shfl_xor(sr[h], off);
        }
    }
    if (lane == 0) {
        #pragma unroll
        for (int h = 0; h < 4; ++h) {
            el[wid * 4 + h] = sl[h];
            er[wid * 4 + h] = sr[h];
        }
    }
}

// ================= CSR build (4-padded rows) =================
__global__ __launch_bounds__(256) void hist_k(const int* __restrict__ dst, int* __restrict__ deg) {
    int e = blockIdx.x * blockDim.x + threadIdx.x;
    if (e < NE) atomicAdd(&deg[dst[e]], 1);
}

__global__ __launch_bounds__(256) void scan1(const int* __restrict__ deg,
                                             int* __restrict__ excl,
                                             int* __restrict__ partials) {
    __shared__ int sh[256];
    int i = blockIdx.x * 256 + threadIdx.x;
    int v = (i < NN) ? ((deg[i] + 3) & ~3) : 0;
    sh[threadIdx.x] = v;
    __syncthreads();
    for (int off = 1; off < 256; off <<= 1) {
        int t = (threadIdx.x >= off) ? sh[threadIdx.x - off] : 0;
        __syncthreads();
        sh[threadIdx.x] += t;
        __syncthreads();
    }
    if (i < NN) excl[i] = sh[threadIdx.x] - v;
    if (threadIdx.x == 255) partials[blockIdx.x] = sh[255];
}

__global__ __launch_bounds__(256) void scan2(int* __restrict__ partials, int nb) {
    __shared__ int sh[256];
    int t = threadIdx.x;
    int v = (t < nb) ? partials[t] : 0;
    sh[t] = v;
    __syncthreads();
    for (int off = 1; off < 256; off <<= 1) {
        int x = (t >= off) ? sh[t - off] : 0;
        __syncthreads();
        sh[t] += x;
        __syncthreads();
    }
    if (t < nb) partials[t] = sh[t] - v;
}

__global__ __launch_bounds__(256) void scan3(const int* __restrict__ excl,
                                             const int* __restrict__ partials,
                                             int* __restrict__ rowptr) {
    int i = blockIdx.x * 256 + threadIdx.x;
    if (i < NN) rowptr[i] = excl[i] + partials[blockIdx.x];
}

__global__ __launch_bounds__(256) void scatter_k(const int* __restrict__ src,
                                                 const int* __restrict__ dst,
                                                 const int* __restrict__ rowptr,
                                                 int* __restrict__ cursor,
                                                 int* __restrict__ ssrc,
                                                 int* __restrict__ sdst) {
    int e = blockIdx.x * blockDim.x + threadIdx.x;
    if (e >= NE) return;
    int d = dst[e];
    int p = atomicAdd(&cursor[d], 1);
    int pos = rowptr[d] + p;
    ssrc[pos] = src[e];
    sdst[pos] = d;
}

// ===== per-CSR-slot unnormalized weights, head-planar =====
__global__ __launch_bounds__(256) void edgew_k(const int* __restrict__ ssrc,
                                               const int* __restrict__ sdst,
                                               const float* __restrict__ el,
                                               const float* __restrict__ er,
                                               float* __restrict__ wcsr) {
    int i = blockIdx.x * blockDim.x + threadIdx.x;
    if (i >= MAXSLOT) return;
    int d = sdst[i];
    float w0 = 0.f, w1 = 0.f, w2 = 0.f, w3 = 0.f;
    if (d >= 0) {
        int s = ssrc[i];
        float4 e_l = *(const float4*)&el[s * 4];
        float4 e_r = *(const float4*)&er[d * 4];
        float v0 = e_l.x + e_r.x; v0 = fmaxf(v0, 0.2f * v0);
        float v1 = e_l.y + e_r.y; v1 = fmaxf(v1, 0.2f * v1);
        float v2 = e_l.z + e_r.z; v2 = fmaxf(v2, 0.2f * v2);
        float v3 = e_l.w + e_r.w; v3 = fmaxf(v3, 0.2f * v3);
        w0 = __expf(v0); w1 = __expf(v1); w2 = __expf(v2); w3 = __expf(v3);
    }
    wcsr[0 * MAXSLOT + i] = w0;
    wcsr[1 * MAXSLOT + i] = w1;
    wcsr[2 * MAXSLOT + i] = w2;
    wcsr[3 * MAXSLOT + i] = w3;
}

// ===== layers 1/2 aggregation: R5 form — 1 wave/node, ushort4 gathers, no prefetch ==
__global__ __launch_bounds__(256) void agg256(const int* __restrict__ rowptr,
                                              const int* __restrict__ deg,
                                              const int* __restrict__ ssrc,
                                              const float* __restrict__ wcsr,
                                              const unsigned short* __restrict__ feat,
                                              unsigned short* __restrict__ ybf) {
    int wid = (blockIdx.x * blockDim.x + threadIdx.x) >> 6;
    int lane = threadIdx.x & 63;
    if (wid >= NN) return;
    int n = wid;
    int start = rowptr[n];
    int cnt4 = (deg[n] + 3) & ~3;
    int head = lane >> 4;
    const float* wch = wcsr + (size_t)head * MAXSLOT;
    float ax = 0.f, ay = 0.f, az = 0.f, aw = 0.f, ssum = 0.f;
    for (int k = 0; k < cnt4; k += 4) {
        int4 sv = *(const int4*)&ssrc[start + k];
        float4 w4 = *(const float4*)&wch[start + k];
        ushort4 f0 = *(const ushort4*)&feat[(size_t)sv.x * 256 + lane * 4];
        ushort4 f1 = *(const ushort4*)&feat[(size_t)sv.y * 256 + lane * 4];
        ushort4 f2 = *(const ushort4*)&feat[(size_t)sv.z * 256 + lane * 4];
        ushort4 f3 = *(const ushort4*)&feat[(size_t)sv.w * 256 + lane * 4];
        ssum += (w4.x + w4.y) + (w4.z + w4.w);
        ax += w4.x * bf2f(f0.x) + w4.y * bf2f(f1.x) + w4.z * bf2f(f2.x) + w4.w * bf2f(f3.x);
        ay += w4.x * bf2f(f0.y) + w4.y * bf2f(f1.y) + w4.z * bf2f(f2.y) + w4.w * bf2f(f3.y);
        az += w4.x * bf2f(f0.z) + w4.y * bf2f(f1.z) + w4.z * bf2f(f2.z) + w4.w * bf2f(f3.z);
        aw += w4.x * bf2f(f0.w) + w4.y * bf2f(f1.w) + w4.z * bf2f(f2.w) + w4.w * bf2f(f3.w);
    }
    float inv = ssum > 0.f ? 1.0f / ssum : 0.f;
    ax *= inv; ay *= inv; az *= inv; aw *= inv;
    ax = ax > 0.f ? ax : (__expf(ax) - 1.f);
    ay = ay > 0.f ? ay : (__expf(ay) - 1.f);
    az = az > 0.f ? az : (__expf(az) - 1.f);
    aw = aw > 0.f ? aw : (__expf(aw) - 1.f);
    ushort4 o;
    o.x = f2bf(ax); o.y = f2bf(ay); o.z = f2bf(az); o.w = f2bf(aw);
    *(ushort4*)&ybf[(size_t)n * 256 + lane * 4] = o;
}

// ===== layer 3: R5 form — aggregate x2 rows -> xagg[N][4][256] bf16, x4 unrolled ====
__global__ __launch_bounds__(256) void agg3(const int* __restrict__ rowptr,
                                            const int* __restrict__ deg,
                                            const int* __restrict__ ssrc,
                                            const float* __restrict__ wcsr,
                                            const unsigned short* __restrict__ x,
                                            unsigned short* __restrict__ xagg) {
    int wid = (blockIdx.x * blockDim.x + threadIdx.x) >> 6;
    int lane = threadIdx.x & 63;
    if (wid >= NN) return;
    int n = wid;
    int start = rowptr[n];
    int cnt4 = (deg[n] + 3) & ~3;
    float acc[4][4] = {};
    float ssum[4] = {};
    for (int k = 0; k < cnt4; k += 4) {
        int4 sv = *(const int4*)&ssrc[start + k];
        float4 w0 = *(const float4*)&wcsr[0 * MAXSLOT + start + k];
        float4 w1 = *(const float4*)&wcsr[1 * MAXSLOT + start + k];
        float4 w2 = *(const float4*)&wcsr[2 * MAXSLOT + start + k];
        float4 w3 = *(const float4*)&wcsr[3 * MAXSLOT + start + k];
        ushort4 xa = *(const ushort4*)&x[(size_t)sv.x * 256 + lane * 4];
        ushort4 xb = *(const ushort4*)&x[(size_t)sv.y * 256 + lane * 4];
        ushort4 xc = *(const ushort4*)&x[(size_t)sv.z * 256 + lane * 4];
        ushort4 xd = *(const ushort4*)&x[(size_t)sv.w * 256 + lane * 4];
        ssum[0] += (w0.x + w0.y) + (w0.z + w0.w);
        ssum[1] += (w1.x + w1.y) + (w1.z + w1.w);
        ssum[2] += (w2.x + w2.y) + (w2.z + w2.w);
        ssum[3] += (w3.x + w3.y) + (w3.z + w3.w);
        float fa[4] = {bf2f(xa.x), bf2f(xa.y), bf2f(xa.z), bf2f(xa.w)};
        float fb[4] = {bf2f(xb.x), bf2f(xb.y), bf2f(xb.z), bf2f(xb.w)};
        float fc[4] = {bf2f(xc.x), bf2f(xc.y), bf2f(xc.z), bf2f(xc.w)};
        float fd[4] = {bf2f(xd.x), bf2f(xd.y), bf2f(xd.z), bf2f(xd.w)};
        #pragma unroll
        for (int d = 0; d < 4; ++d) {
            acc[0][d] += w0.x * fa[d] + w0.y * fb[d] + w0.z * fc[d] + w0.w * fd[d];
            acc[1][d] += w1.x * fa[d] + w1.y * fb[d] + w1.z * fc[d] + w1.w * fd[d];
            acc[2][d] += w2.x * fa[d] + w2.y * fb[d] + w2.z * fc[d] + w2.w * fd[d];
            acc[3][d] += w3.x * fa[d] + w3.y * fb[d] + w3.z * fc[d] + w3.w * fd[d];
        }
    }
    #pragma unroll
    for (int h = 0; h < 4; ++h) {
        float inv = ssum[h] > 0.f ? 1.f / ssum[h] : 0.f;
        ushort4 o;
        o.x = f2bf(acc[h][0] * inv); o.y = f2bf(acc[h][1] * inv);
        o.z = f2bf(acc[h][2] * inv); o.w = f2bf(acc[h][3] * inv);
        *(ushort4*)&xagg[(size_t)n * 1024 + h * 256 + lane * 4] = o;
    }
}

extern "C" void kernel_launch(void* const* d_in, const int* in_sizes, int n_in,
                              void* d_out, int out_size, void* d_ws, size_t ws_size,
                              hipStream_t stream) {
    const float* h   = (const float*)d_in[0];
    const int*   src = (const int*)d_in[1];
    const int*   dst = (const int*)d_in[2];
    const float* W1  = (const float*)d_in[3];
    const float* al1 = (const float*)d_in[4];
    const float* ar1 = (const float*)d_in[5];
    const float* W2  = (const float*)d_in[6];
    const float* al2 = (const float*)d_in[7];
    const float* ar2 = (const float*)d_in[8];
    const float* W3  = (const float*)d_in[9];
    const float* al3 = (const float*)d_in[10];
    const float* ar3 = (const float*)d_in[11];
    float* out = (float*)d_out;

    float* ws = (float*)d_ws;
    unsigned short* x_bf    = (unsigned short*)ws;
    unsigned short* h_bf    = (unsigned short*)(ws + 6400000);
    unsigned short* feat_bf = (unsigned short*)(ws + 12800000);
    unsigned short* xagg    = (unsigned short*)(ws + 6400000);  // overlays h_bf+feat_bf (dead by L3)
    float* el  = ws + 32000000;
    float* er  = ws + 32200000;
    float* wl3 = ws + 32400000;
    float* wr3 = ws + 32401024;
    unsigned short* BT1   = (unsigned short*)(ws + 32402048);
    unsigned short* BT2   = (unsigned short*)(ws + 32434816);
    unsigned short* BTcat = (unsigned short*)(ws + 32467584);
    float* wcsr = ws + 32533120;                 // 4 x 600,000 floats
    int* ibase  = (int*)(ws + 34933120);
    int* deg      = ibase;
    int* excl     = ibase + 50000;
    int* partials = ibase + 100000;
    int* rowptr   = ibase + 100256;
    int* cursor   = ibase + 150256;
    int* ssrc     = ibase + 200256;
    int* sdst     = ibase + 800256;

    const int NB = (NN + 255) / 256;
    const int SLOT_BLOCKS = (MAXSLOT + 255) / 256;

    // ---- CSR build (4-padded rows; pads: ssrc=0, sdst=-1) ----
    hipMemsetAsync(deg, 0, NN * sizeof(int), stream);
    hipMemsetAsync(cursor, 0, NN * sizeof(int), stream);
    hipMemsetAsync(ssrc, 0, MAXSLOT * sizeof(int), stream);
    hipMemsetAsync(sdst, 0xFF, MAXSLOT * sizeof(int), stream);
    hist_k<<<(NE + 255) / 256, 256, 0, stream>>>(dst, deg);
    scan1<<<NB, 256, 0, stream>>>(deg, excl, partials);
    scan2<<<1, 256, 0, stream>>>(partials, NB);
    scan3<<<NB, 256, 0, stream>>>(excl, partials, rowptr);
    scatter_k<<<(NE + 255) / 256, 256, 0, stream>>>(src, dst, rowptr, cursor, ssrc, sdst);

    // ---- casts / weight prep ----
    cast_x<<<(NN * 256 / 4 + 255) / 256, 256, 0, stream>>>(h, h_bf, NN * 256 / 4);
    cast_BT<<<(256 * 256 + 255) / 256, 256, 0, stream>>>(W1, BT1, 256, 256);
    cast_BT<<<(256 * 256 + 255) / 256, 256, 0, stream>>>(W2, BT2, 256, 256);
    cast_BTcat<<<512, 256, 0, stream>>>(W3, BTcat);
    wvec3_k<<<8, 256, 0, stream>>>(W3, al3, ar3, wl3, wr3);

    dim3 g256((NN + 127) / 128, 2);
    dim3 gOut((NN + 127) / 128, 1);
    const int WAVE_BLOCKS = (NN * 64 + 255) / 256;   // one wave per node

    // ---- layer 1 ----
    gemm_bf16<<<g256, 256, 0, stream>>>(h_bf, BT1, nullptr, feat_bf, al1, ar1, el, er, NN, 256, 256);
    edgew_k<<<SLOT_BLOCKS, 256, 0, stream>>>(ssrc, sdst, el, er, wcsr);
    agg256<<<WAVE_BLOCKS, 256, 0, stream>>>(rowptr, deg, ssrc, wcsr, feat_bf, x_bf);

    // ---- layer 2 ----
    gemm_bf16<<<g256, 256, 0, stream>>>(x_bf, BT2, nullptr, feat_bf, al2, ar2, el, er, NN, 256, 256);
    edgew_k<<<SLOT_BLOCKS, 256, 0, stream>>>(ssrc, sdst, el, er, wcsr);
    agg256<<<WAVE_BLOCKS, 256, 0, stream>>>(rowptr, deg, ssrc, wcsr, feat_bf, x_bf);

    // ---- layer 3 (input-side aggregation; exact reorder of reference math) ----
    elr3_k<<<WAVE_BLOCKS, 256, 0, stream>>>(x_bf, wl3, wr3, el, er);
    edgew_k<<<SLOT_BLOCKS, 256, 0, stream>>>(ssrc, sdst, el, er, wcsr);
    agg3<<<WAVE_BLOCKS, 256, 0, stream>>>(rowptr, deg, ssrc, wcsr, x_bf, xagg);
    gemm_bf16<<<gOut, 256, 0, stream>>>(xagg, BTcat, out, nullptr, nullptr, nullptr, nullptr, nullptr, NN, NC, 1024);
}

// Round 9
// 434.034 us; speedup vs baseline: 1.0664x; 1.0664x over previous
//
#include <hip/hip_runtime.h>
#include <cstddef>

#define NN 50000
#define NE 400000
#define NH 4
#define NC 121
#define MAXSLOT 600000   // NE + 4*NN upper bound on padded CSR slots

typedef __attribute__((ext_vector_type(8))) short short8;
typedef __attribute__((ext_vector_type(4))) float f32x4;
typedef __attribute__((ext_vector_type(2))) float f32x2;

// fp32 -> bf16 round-to-nearest-even
static __device__ __forceinline__ unsigned short f2bf(float f) {
    unsigned u = __float_as_uint(f);
    u += 0x7fffu + ((u >> 16) & 1u);
    return (unsigned short)(u >> 16);
}
static __device__ __forceinline__ float bf2f(unsigned short u) {
    return __uint_as_float(((unsigned)u) << 16);
}
// dword holding 2 bf16 -> 2 floats
static __device__ __forceinline__ f32x2 bfpair(unsigned u) {
    f32x2 r;
    r.x = __uint_as_float(u << 16);
    r.y = __uint_as_float(u & 0xffff0000u);
    return r;
}

// ================= cast kernels =================
__global__ __launch_bounds__(256) void cast_x(const float* __restrict__ in,
                                              unsigned short* __restrict__ out, int n4) {
    int i = blockIdx.x * blockDim.x + threadIdx.x;
    if (i >= n4) return;
    float4 v = *(const float4*)&in[i * 4];
    ushort4 o;
    o.x = f2bf(v.x); o.y = f2bf(v.y); o.z = f2bf(v.z); o.w = f2bf(v.w);
    *(ushort4*)&out[i * 4] = o;
}

__global__ __launch_bounds__(256) void cast_BT(const float* __restrict__ B,
                                               unsigned short* __restrict__ BT,
                                               int N, int Npad) {
    int i = blockIdx.x * blockDim.x + threadIdx.x;
    if (i >= Npad * 256) return;
    int n = i >> 8, k = i & 255;
    float v = (n < N) ? B[(size_t)k * N + n] : 0.f;
    BT[i] = f2bf(v);
}

// W3[256][484] -> BTcat[128][1024] bf16: BTcat[c][h*256+k] = 0.25*W3[k][h*121+c]
__global__ __launch_bounds__(256) void cast_BTcat(const float* __restrict__ W3,
                                                  unsigned short* __restrict__ BT) {
    int i = blockIdx.x * blockDim.x + threadIdx.x;
    if (i >= 128 * 1024) return;
    int c = i >> 10, kk = i & 1023;
    int h = kk >> 8, k = kk & 255;
    float v = (c < NC) ? 0.25f * W3[(size_t)k * 484 + h * NC + c] : 0.f;
    BT[i] = f2bf(v);
}

// wl3[h*256+k] = sum_d W3[k][h*121+d]*al3[h][d]; wr3 likewise
__global__ __launch_bounds__(256) void wvec3_k(const float* __restrict__ W3,
                                               const float* __restrict__ al3,
                                               const float* __restrict__ ar3,
                                               float* __restrict__ wl3,
                                               float* __restrict__ wr3) {
    int i = blockIdx.x * blockDim.x + threadIdx.x;
    if (i >= 2048) return;
    int j = i & 1023;
    int h = j >> 8, k = j & 255;
    const float* a = (i < 1024) ? al3 : ar3;
    const float* wrow = W3 + (size_t)k * 484 + h * NC;
    const float* arow = a + h * NC;
    float s = 0.f;
    for (int d = 0; d < NC; ++d) s += wrow[d] * arow[d];
    if (i < 1024) wl3[j] = s; else wr3[j] = s;
}

// ================= MFMA GEMM with optional fused attention-logit epilogue ==========
__global__ __launch_bounds__(256) void gemm_bf16(const unsigned short* __restrict__ A,
                                                 const unsigned short* __restrict__ BT,
                                                 float* __restrict__ Cf,
                                                 unsigned short* __restrict__ Cb,
                                                 const float* __restrict__ al,
                                                 const float* __restrict__ ar,
                                                 float* __restrict__ el,
                                                 float* __restrict__ er,
                                                 int M, int Nout, int K) {
    __shared__ __align__(16) unsigned short Alds[128 * 32];
    __shared__ __align__(16) unsigned short Blds[128 * 32];
    const int tid = threadIdx.x;
    const int wave = tid >> 6;
    const int lane = tid & 63;
    const int quad = lane >> 4;
    const int ml = lane & 15;
    const int m0 = blockIdx.x * 128;
    const int n0 = blockIdx.y * 128;
    const int wm0 = (wave >> 1) * 64;
    const int wn0 = (wave & 1) * 64;
    const int r = tid >> 2;
    const int c8 = (tid & 3) * 8;

    f32x4 acc[4][4] = {};

    for (int k0 = 0; k0 < K; k0 += 32) {
        #pragma unroll
        for (int p = 0; p < 2; ++p) {
            int rr = r + p * 64;
            int m = m0 + rr;
            uint4 va = make_uint4(0u, 0u, 0u, 0u);
            if (m < M) va = *(const uint4*)&A[(size_t)m * K + k0 + c8];
            *(uint4*)&Alds[rr * 32 + c8] = va;
            int n = n0 + rr;
            uint4 vb = *(const uint4*)&BT[(size_t)n * K + k0 + c8];
            *(uint4*)&Blds[rr * 32 + c8] = vb;
        }
        __syncthreads();

        short8 af[4], bf[4];
        #pragma unroll
        for (int i = 0; i < 4; ++i)
            af[i] = *(const short8*)&Alds[(wm0 + i * 16 + ml) * 32 + quad * 8];
        #pragma unroll
        for (int j = 0; j < 4; ++j)
            bf[j] = *(const short8*)&Blds[(wn0 + j * 16 + ml) * 32 + quad * 8];
        #pragma unroll
        for (int i = 0; i < 4; ++i)
            #pragma unroll
            for (int j = 0; j < 4; ++j)
                acc[i][j] = __builtin_amdgcn_mfma_f32_16x16x32_bf16(af[i], bf[j], acc[i][j], 0, 0, 0);
        __syncthreads();
    }

    // C/D layout: col = lane&15, row = quad*4 + reg
    #pragma unroll
    for (int i = 0; i < 4; ++i) {
        #pragma unroll
        for (int reg = 0; reg < 4; ++reg) {
            int m = m0 + wm0 + i * 16 + quad * 4 + reg;
            if (m >= M) continue;
            #pragma unroll
            for (int j = 0; j < 4; ++j) {
                int n = n0 + wn0 + j * 16 + ml;
                if (n < Nout) {
                    if (Cb) Cb[(size_t)m * Nout + n] = f2bf(acc[i][j][reg]);
                    else    Cf[(size_t)m * Nout + n] = acc[i][j][reg];
                }
            }
        }
    }

    // ---- fused attention logits (Nout==256 path only): wave's 64 cols = one head ----
    if (el) {
        int head = (n0 + wn0) >> 6;
        float alv[4], arv[4];
        #pragma unroll
        for (int j = 0; j < 4; ++j) {
            alv[j] = al[head * 64 + j * 16 + ml];
            arv[j] = ar[head * 64 + j * 16 + ml];
        }
        #pragma unroll
        for (int i = 0; i < 4; ++i) {
            #pragma unroll
            for (int reg = 0; reg < 4; ++reg) {
                float sl = 0.f, sr = 0.f;
                #pragma unroll
                for (int j = 0; j < 4; ++j) {
                    float v = acc[i][j][reg];
                    sl += v * alv[j];
                    sr += v * arv[j];
                }
                #pragma unroll
                for (int off = 1; off < 16; off <<= 1) {
                    sl += __shfl_xor(sl, off);
                    sr += __shfl_xor(sr, off);
                }
                int m = m0 + wm0 + i * 16 + quad * 4 + reg;
                if (ml == 0 && m < M) {
                    el[m * 4 + head] = sl;
                    er[m * 4 + head] = sr;
                }
            }
        }
    }
}

// ================= CSR build (4-padded rows) =================
__global__ __launch_bounds__(256) void hist_k(const int* __restrict__ dst, int* __restrict__ deg) {
    int e = blockIdx.x * blockDim.x + threadIdx.x;
    if (e < NE) atomicAdd(&deg[dst[e]], 1);
}

__global__ __launch_bounds__(256) void scan1(const int* __restrict__ deg,
                                             int* __restrict__ excl,
                                             int* __restrict__ partials) {
    __shared__ int sh[256];
    int i = blockIdx.x * 256 + threadIdx.x;
    int v = (i < NN) ? ((deg[i] + 3) & ~3) : 0;
    sh[threadIdx.x] = v;
    __syncthreads();
    for (int off = 1; off < 256; off <<= 1) {
        int t = (threadIdx.x >= off) ? sh[threadIdx.x - off] : 0;
        __syncthreads();
        sh[threadIdx.x] += t;
        __syncthreads();
    }
    if (i < NN) excl[i] = sh[threadIdx.x] - v;
    if (threadIdx.x == 255) partials[blockIdx.x] = sh[255];
}

__global__ __launch_bounds__(256) void scan2(int* __restrict__ partials, int nb) {
    __shared__ int sh[256];
    int t = threadIdx.x;
    int v = (t < nb) ? partials[t] : 0;
    sh[t] = v;
    __syncthreads();
    for (int off = 1; off < 256; off <<= 1) {
        int x = (t >= off) ? sh[t - off] : 0;
        __syncthreads();
        sh[t] += x;
        __syncthreads();
    }
    if (t < nb) partials[t] = sh[t] - v;
}

__global__ __launch_bounds__(256) void scan3(const int* __restrict__ excl,
                                             const int* __restrict__ partials,
                                             int* __restrict__ rowptr) {
    int i = blockIdx.x * 256 + threadIdx.x;
    if (i < NN) rowptr[i] = excl[i] + partials[blockIdx.x];
}

__global__ __launch_bounds__(256) void scatter_k(const int* __restrict__ src,
                                                 const int* __restrict__ dst,
                                                 const int* __restrict__ rowptr,
                                                 int* __restrict__ cursor,
                                                 int* __restrict__ ssrc,
                                                 int* __restrict__ sdst) {
    int e = blockIdx.x * blockDim.x + threadIdx.x;
    if (e >= NE) return;
    int d = dst[e];
    int p = atomicAdd(&cursor[d], 1);
    int pos = rowptr[d] + p;
    ssrc[pos] = src[e];
    sdst[pos] = d;
}

// ===== per-CSR-slot unnormalized weights, head-planar =====
__global__ __launch_bounds__(256) void edgew_k(const int* __restrict__ ssrc,
                                               const int* __restrict__ sdst,
                                               const float* __restrict__ el,
                                               const float* __restrict__ er,
                                               float* __restrict__ wcsr) {
    int i = blockIdx.x * blockDim.x + threadIdx.x;
    if (i >= MAXSLOT) return;
    int d = sdst[i];
    float w0 = 0.f, w1 = 0.f, w2 = 0.f, w3 = 0.f;
    if (d >= 0) {
        int s = ssrc[i];
        float4 e_l = *(const float4*)&el[s * 4];
        float4 e_r = *(const float4*)&er[d * 4];
        float v0 = e_l.x + e_r.x; v0 = fmaxf(v0, 0.2f * v0);
        float v1 = e_l.y + e_r.y; v1 = fmaxf(v1, 0.2f * v1);
        float v2 = e_l.z + e_r.z; v2 = fmaxf(v2, 0.2f * v2);
        float v3 = e_l.w + e_r.w; v3 = fmaxf(v3, 0.2f * v3);
        w0 = __expf(v0); w1 = __expf(v1); w2 = __expf(v2); w3 = __expf(v3);
    }
    wcsr[0 * MAXSLOT + i] = w0;
    wcsr[1 * MAXSLOT + i] = w1;
    wcsr[2 * MAXSLOT + i] = w2;
    wcsr[3 * MAXSLOT + i] = w3;
}

// ===== layers 1/2 aggregation: 1 wave/node, ushort4 gathers, f32x2 packed acc ======
// If wl3 != nullptr (layer-2 instance), fused epilogue computes layer-3 logits
// el3[n,h] = sum_k x2[n,k]*wl3[h*256+k] from the fp32 post-ELU values in registers.
__global__ __launch_bounds__(256) void agg256(const int* __restrict__ rowptr,
                                              const int* __restrict__ deg,
                                              const int* __restrict__ ssrc,
                                              const float* __restrict__ wcsr,
                                              const unsigned short* __restrict__ feat,
                                              unsigned short* __restrict__ ybf,
                                              const float* __restrict__ wl3,
                                              const float* __restrict__ wr3,
                                              float* __restrict__ el3,
                                              float* __restrict__ er3) {
    int wid = (blockIdx.x * blockDim.x + threadIdx.x) >> 6;
    int lane = threadIdx.x & 63;
    if (wid >= NN) return;
    int n = wid;
    int start = rowptr[n];
    int cnt4 = (deg[n] + 3) & ~3;
    int head = lane >> 4;
    const float* wch = wcsr + (size_t)head * MAXSLOT;
    f32x2 a01 = {0.f, 0.f}, a23 = {0.f, 0.f};
    float ssum = 0.f;
    for (int k = 0; k < cnt4; k += 4) {
        int4 sv = *(const int4*)&ssrc[start + k];
        float4 w4 = *(const float4*)&wch[start + k];
        uint2 u0 = *(const uint2*)&feat[(size_t)sv.x * 256 + lane * 4];
        uint2 u1 = *(const uint2*)&feat[(size_t)sv.y * 256 + lane * 4];
        uint2 u2 = *(const uint2*)&feat[(size_t)sv.z * 256 + lane * 4];
        uint2 u3 = *(const uint2*)&feat[(size_t)sv.w * 256 + lane * 4];
        ssum += (w4.x + w4.y) + (w4.z + w4.w);
        a01 += w4.x * bfpair(u0.x); a23 += w4.x * bfpair(u0.y);
        a01 += w4.y * bfpair(u1.x); a23 += w4.y * bfpair(u1.y);
        a01 += w4.z * bfpair(u2.x); a23 += w4.z * bfpair(u2.y);
        a01 += w4.w * bfpair(u3.x); a23 += w4.w * bfpair(u3.y);
    }
    float inv = ssum > 0.f ? 1.0f / ssum : 0.f;
    float r0 = a01.x * inv, r1 = a01.y * inv, r2 = a23.x * inv, r3 = a23.y * inv;
    r0 = r0 > 0.f ? r0 : (__expf(r0) - 1.f);
    r1 = r1 > 0.f ? r1 : (__expf(r1) - 1.f);
    r2 = r2 > 0.f ? r2 : (__expf(r2) - 1.f);
    r3 = r3 > 0.f ? r3 : (__expf(r3) - 1.f);
    ushort4 o;
    o.x = f2bf(r0); o.y = f2bf(r1); o.z = f2bf(r2); o.w = f2bf(r3);
    *(ushort4*)&ybf[(size_t)n * 256 + lane * 4] = o;

    // ---- fused layer-3 logits (layer-2 instance only) ----
    if (wl3) {
        float sl[4], sr[4];
        #pragma unroll
        for (int h = 0; h < 4; ++h) {
            float4 a4 = *(const float4*)&wl3[h * 256 + lane * 4];
            float4 b4 = *(const float4*)&wr3[h * 256 + lane * 4];
            sl[h] = r0 * a4.x + r1 * a4.y + r2 * a4.z + r3 * a4.w;
            sr[h] = r0 * b4.x + r1 * b4.y + r2 * b4.z + r3 * b4.w;
        }
        #pragma unroll
        for (int off = 32; off; off >>= 1) {
            #pragma unroll
            for (int h = 0; h < 4; ++h) {
                sl[h] += __shfl_xor(sl[h], off);
                sr[h] += __shfl_xor(sr[h], off);
            }
        }
        if (lane == 0) {
            #pragma unroll
            for (int h = 0; h < 4; ++h) {
                el3[n * 4 + h] = sl[h];
                er3[n * 4 + h] = sr[h];
            }
        }
    }
}

// ===== layer 3: aggregate x2 rows -> xagg[N][4][256] bf16, f32x2 packed acc ========
__global__ __launch_bounds__(256) void agg3(const int* __restrict__ rowptr,
                                            const int* __restrict__ deg,
                                            const int* __restrict__ ssrc,
                                            const float* __restrict__ wcsr,
                                            const unsigned short* __restrict__ x,
                                            unsigned short* __restrict__ xagg) {
    int wid = (blockIdx.x * blockDim.x + threadIdx.x) >> 6;
    int lane = threadIdx.x & 63;
    if (wid >= NN) return;
    int n = wid;
    int start = rowptr[n];
    int cnt4 = (deg[n] + 3) & ~3;
    f32x2 accA[4] = {}, accB[4] = {};
    float ssum[4] = {};
    for (int k = 0; k < cnt4; k += 4) {
        int4 sv = *(const int4*)&ssrc[start + k];
        float4 w0 = *(const float4*)&wcsr[0 * MAXSLOT + start + k];
        float4 w1 = *(const float4*)&wcsr[1 * MAXSLOT + start + k];
        float4 w2 = *(const float4*)&wcsr[2 * MAXSLOT + start + k];
        float4 w3 = *(const float4*)&wcsr[3 * MAXSLOT + start + k];
        uint2 u0 = *(const uint2*)&x[(size_t)sv.x * 256 + lane * 4];
        uint2 u1 = *(const uint2*)&x[(size_t)sv.y * 256 + lane * 4];
        uint2 u2 = *(const uint2*)&x[(size_t)sv.z * 256 + lane * 4];
        uint2 u3 = *(const uint2*)&x[(size_t)sv.w * 256 + lane * 4];
        ssum[0] += (w0.x + w0.y) + (w0.z + w0.w);
        ssum[1] += (w1.x + w1.y) + (w1.z + w1.w);
        ssum[2] += (w2.x + w2.y) + (w2.z + w2.w);
        ssum[3] += (w3.x + w3.y) + (w3.z + w3.w);
        f32x2 fa = bfpair(u0.x), fA = bfpair(u0.y);
        f32x2 fb = bfpair(u1.x), fB = bfpair(u1.y);
        f32x2 fc = bfpair(u2.x), fC = bfpair(u2.y);
        f32x2 fd = bfpair(u3.x), fD = bfpair(u3.y);
        accA[0] += w0.x * fa + w0.y * fb + w0.z * fc + w0.w * fd;
        accB[0] += w0.x * fA + w0.y * fB + w0.z * fC + w0.w * fD;
        accA[1] += w1.x * fa + w1.y * fb + w1.z * fc + w1.w * fd;
        accB[1] += w1.x * fA + w1.y * fB + w1.z * fC + w1.w * fD;
        accA[2] += w2.x * fa + w2.y * fb + w2.z * fc + w2.w * fd;
        accB[2] += w2.x * fA + w2.y * fB + w2.z * fC + w2.w * fD;
        accA[3] += w3.x * fa + w3.y * fb + w3.z * fc + w3.w * fd;
        accB[3] += w3.x * fA + w3.y * fB + w3.z * fC + w3.w * fD;
    }
    #pragma unroll
    for (int h = 0; h < 4; ++h) {
        float inv = ssum[h] > 0.f ? 1.f / ssum[h] : 0.f;
        ushort4 o;
        o.x = f2bf(accA[h].x * inv); o.y = f2bf(accA[h].y * inv);
        o.z = f2bf(accB[h].x * inv); o.w = f2bf(accB[h].y * inv);
        *(ushort4*)&xagg[(size_t)n * 1024 + h * 256 + lane * 4] = o;
    }
}

extern "C" void kernel_launch(void* const* d_in, const int* in_sizes, int n_in,
                              void* d_out, int out_size, void* d_ws, size_t ws_size,
                              hipStream_t stream) {
    const float* h   = (const float*)d_in[0];
    const int*   src = (const int*)d_in[1];
    const int*   dst = (const int*)d_in[2];
    const float* W1  = (const float*)d_in[3];
    const float* al1 = (const float*)d_in[4];
    const float* ar1 = (const float*)d_in[5];
    const float* W2  = (const float*)d_in[6];
    const float* al2 = (const float*)d_in[7];
    const float* ar2 = (const float*)d_in[8];
    const float* W3  = (const float*)d_in[9];
    const float* al3 = (const float*)d_in[10];
    const float* ar3 = (const float*)d_in[11];
    float* out = (float*)d_out;

    float* ws = (float*)d_ws;
    unsigned short* x_bf    = (unsigned short*)ws;
    unsigned short* h_bf    = (unsigned short*)(ws + 6400000);
    unsigned short* feat_bf = (unsigned short*)(ws + 12800000);
    unsigned short* xagg    = (unsigned short*)(ws + 6400000);  // overlays h_bf+feat_bf (dead by L3)
    float* el  = ws + 32000000;
    float* er  = ws + 32200000;
    float* wl3 = ws + 32400000;
    float* wr3 = ws + 32401024;
    unsigned short* BT1   = (unsigned short*)(ws + 32402048);
    unsigned short* BT2   = (unsigned short*)(ws + 32434816);
    unsigned short* BTcat = (unsigned short*)(ws + 32467584);
    float* wcsr = ws + 32533120;                 // 4 x 600,000 floats
    int* ibase  = (int*)(ws + 34933120);
    int* deg      = ibase;                       // 50,000
    int* cursor   = ibase + 50000;               // 50,000 (adjacent to deg: one memset)
    int* excl     = ibase + 100000;              // 50,000
    int* partials = ibase + 150000;              // 256
    int* rowptr   = ibase + 150256;              // 50,000
    int* ssrc     = ibase + 200256;              // 600,000
    int* sdst     = ibase + 800256;              // 600,000

    const int NB = (NN + 255) / 256;
    const int SLOT_BLOCKS = (MAXSLOT + 255) / 256;

    // ---- CSR build (4-padded rows; pads: ssrc=0, sdst=-1) ----
    hipMemsetAsync(deg, 0, 2 * NN * sizeof(int), stream);   // deg + cursor
    hipMemsetAsync(ssrc, 0, MAXSLOT * sizeof(int), stream);
    hipMemsetAsync(sdst, 0xFF, MAXSLOT * sizeof(int), stream);
    hist_k<<<(NE + 255) / 256, 256, 0, stream>>>(dst, deg);
    scan1<<<NB, 256, 0, stream>>>(deg, excl, partials);
    scan2<<<1, 256, 0, stream>>>(partials, NB);
    scan3<<<NB, 256, 0, stream>>>(excl, partials, rowptr);
    scatter_k<<<(NE + 255) / 256, 256, 0, stream>>>(src, dst, rowptr, cursor, ssrc, sdst);

    // ---- casts / weight prep ----
    cast_x<<<(NN * 256 / 4 + 255) / 256, 256, 0, stream>>>(h, h_bf, NN * 256 / 4);
    cast_BT<<<(256 * 256 + 255) / 256, 256, 0, stream>>>(W1, BT1, 256, 256);
    cast_BT<<<(256 * 256 + 255) / 256, 256, 0, stream>>>(W2, BT2, 256, 256);
    cast_BTcat<<<512, 256, 0, stream>>>(W3, BTcat);
    wvec3_k<<<8, 256, 0, stream>>>(W3, al3, ar3, wl3, wr3);

    dim3 g256((NN + 127) / 128, 2);
    dim3 gOut((NN + 127) / 128, 1);
    const int WAVE_BLOCKS = (NN * 64 + 255) / 256;   // one wave per node

    // ---- layer 1 ----
    gemm_bf16<<<g256, 256, 0, stream>>>(h_bf, BT1, nullptr, feat_bf, al1, ar1, el, er, NN, 256, 256);
    edgew_k<<<SLOT_BLOCKS, 256, 0, stream>>>(ssrc, sdst, el, er, wcsr);
    agg256<<<WAVE_BLOCKS, 256, 0, stream>>>(rowptr, deg, ssrc, wcsr, feat_bf, x_bf,
                                            nullptr, nullptr, nullptr, nullptr);

    // ---- layer 2 (fused layer-3 logit epilogue) ----
    gemm_bf16<<<g256, 256, 0, stream>>>(x_bf, BT2, nullptr, feat_bf, al2, ar2, el, er, NN, 256, 256);
    edgew_k<<<SLOT_BLOCKS, 256, 0, stream>>>(ssrc, sdst, el, er, wcsr);
    agg256<<<WAVE_BLOCKS, 256, 0, stream>>>(rowptr, deg, ssrc, wcsr, feat_bf, x_bf,
                                            wl3, wr3, el, er);

    // ---- layer 3 (input-side aggregation; exact reorder of reference math) ----
    edgew_k<<<SLOT_BLOCKS, 256, 0, stream>>>(ssrc, sdst, el, er, wcsr);
    agg3<<<WAVE_BLOCKS, 256, 0, stream>>>(rowptr, deg, ssrc, wcsr, x_bf, xagg);
    gemm_bf16<<<gOut, 256, 0, stream>>>(xagg, BTcat, out, nullptr, nullptr, nullptr, nullptr, nullptr, NN, NC, 1024);
}

// Round 10
// 413.258 us; speedup vs baseline: 1.1200x; 1.0503x over previous
//
#include <hip/hip_runtime.h>
#include <cstddef>

#define NN 50000
#define NE 400000
#define NH 4
#define NC 121
#define MAXSLOT 600000   // NE + 4*NN upper bound on padded CSR slots

typedef __attribute__((ext_vector_type(8))) short short8;
typedef __attribute__((ext_vector_type(4))) float f32x4;
typedef __attribute__((ext_vector_type(2))) float f32x2;

// fp32 -> bf16 round-to-nearest-even
static __device__ __forceinline__ unsigned short f2bf(float f) {
    unsigned u = __float_as_uint(f);
    u += 0x7fffu + ((u >> 16) & 1u);
    return (unsigned short)(u >> 16);
}
static __device__ __forceinline__ float bf2f(unsigned short u) {
    return __uint_as_float(((unsigned)u) << 16);
}
// dword holding 2 bf16 -> 2 floats
static __device__ __forceinline__ f32x2 bfpair(unsigned u) {
    f32x2 r;
    r.x = __uint_as_float(u << 16);
    r.y = __uint_as_float(u & 0xffff0000u);
    return r;
}
// async global->LDS, 16B per lane; LDS dest = wave-uniform base + lane*16
static __device__ __forceinline__ void load_lds16(const unsigned short* g, unsigned short* l) {
    __builtin_amdgcn_global_load_lds(
        (const __attribute__((address_space(1))) unsigned*)g,
        (__attribute__((address_space(3))) unsigned*)l, 16, 0, 0);
}

// ================= fused prep: cast_x + BT1 + BT2 + BTcat + wvec3 =================
#define PREP_X    3200000            // NN*256/4 float4->ushort4 items
#define PREP_BT1  (PREP_X + 65536)
#define PREP_BT2  (PREP_BT1 + 65536)
#define PREP_CAT  (PREP_BT2 + 131072)
#define PREP_WV   (PREP_CAT + 2048)
__global__ __launch_bounds__(256) void prep_k(const float* __restrict__ h,
                                              const float* __restrict__ W1,
                                              const float* __restrict__ W2,
                                              const float* __restrict__ W3,
                                              const float* __restrict__ al3,
                                              const float* __restrict__ ar3,
                                              unsigned short* __restrict__ h_bf,
                                              unsigned short* __restrict__ BT1,
                                              unsigned short* __restrict__ BT2,
                                              unsigned short* __restrict__ BTcat,
                                              float* __restrict__ wl3,
                                              float* __restrict__ wr3) {
    int i = blockIdx.x * blockDim.x + threadIdx.x;
    if (i < PREP_X) {
        float4 v = *(const float4*)&h[(size_t)i * 4];
        ushort4 o;
        o.x = f2bf(v.x); o.y = f2bf(v.y); o.z = f2bf(v.z); o.w = f2bf(v.w);
        *(ushort4*)&h_bf[(size_t)i * 4] = o;
    } else if (i < PREP_BT1) {
        int j = i - PREP_X;
        int n = j >> 8, k = j & 255;
        BT1[j] = f2bf(W1[(size_t)k * 256 + n]);
    } else if (i < PREP_BT2) {
        int j = i - PREP_BT1;
        int n = j >> 8, k = j & 255;
        BT2[j] = f2bf(W2[(size_t)k * 256 + n]);
    } else if (i < PREP_CAT) {
        int j = i - PREP_BT2;
        int c = j >> 10, kk = j & 1023;
        int hh = kk >> 8, k = kk & 255;
        float v = (c < NC) ? 0.25f * W3[(size_t)k * 484 + hh * NC + c] : 0.f;
        BTcat[j] = f2bf(v);
    } else if (i < PREP_WV) {
        int j = (i - PREP_CAT) & 1023;
        int sel = (i - PREP_CAT) >> 10;
        int hh = j >> 8, k = j & 255;
        const float* a = sel ? ar3 : al3;
        const float* wrow = W3 + (size_t)k * 484 + hh * NC;
        const float* arow = a + hh * NC;
        float s = 0.f;
        for (int d = 0; d < NC; ++d) s += wrow[d] * arow[d];
        if (sel) wr3[j] = s; else wl3[j] = s;
    }
}

// ================= MFMA GEMM, global_load_lds staging, fused logit epilogue ========
__global__ __launch_bounds__(256) void gemm_bf16(const unsigned short* __restrict__ A,
                                                 const unsigned short* __restrict__ BT,
                                                 float* __restrict__ Cf,
                                                 unsigned short* __restrict__ Cb,
                                                 const float* __restrict__ al,
                                                 const float* __restrict__ ar,
                                                 float* __restrict__ el,
                                                 float* __restrict__ er,
                                                 int M, int Nout, int K) {
    __shared__ __align__(16) unsigned short Alds[128 * 32];
    __shared__ __align__(16) unsigned short Blds[128 * 32];
    const int tid = threadIdx.x;
    const int wave = tid >> 6;
    const int lane = tid & 63;
    const int quad = lane >> 4;
    const int ml = lane & 15;
    const int m0 = blockIdx.x * 128;
    const int n0 = blockIdx.y * 128;
    const int wm0 = (wave >> 1) * 64;
    const int wn0 = (wave & 1) * 64;

    // staging: lane i of wave w covers row w*16+(i>>2) (+p*64), k-offset (i&3)*8;
    // LDS bytes land at (w*1024 + p*4096) + i*16 == row*64 + (i&3)*16 (contiguous).
    const unsigned short* Ab = A + (size_t)(m0 + wave * 16 + (lane >> 2)) * K + (lane & 3) * 8;
    const unsigned short* Bb = BT + (size_t)(n0 + wave * 16 + (lane >> 2)) * K + (lane & 3) * 8;
    unsigned short* AldsW = Alds + wave * 512;   // ushort units: 512*2B = 1024B per wave
    unsigned short* BldsW = Blds + wave * 512;

    f32x4 acc[4][4] = {};

    for (int k0 = 0; k0 < K; k0 += 32) {
        #pragma unroll
        for (int p = 0; p < 2; ++p) {
            load_lds16(Ab + (size_t)(p * 64) * K + k0, AldsW + p * 2048);
            load_lds16(Bb + (size_t)(p * 64) * K + k0, BldsW + p * 2048);
        }
        __syncthreads();

        short8 af[4], bf[4];
        #pragma unroll
        for (int i = 0; i < 4; ++i)
            af[i] = *(const short8*)&Alds[(wm0 + i * 16 + ml) * 32 + quad * 8];
        #pragma unroll
        for (int j = 0; j < 4; ++j)
            bf[j] = *(const short8*)&Blds[(wn0 + j * 16 + ml) * 32 + quad * 8];
        #pragma unroll
        for (int i = 0; i < 4; ++i)
            #pragma unroll
            for (int j = 0; j < 4; ++j)
                acc[i][j] = __builtin_amdgcn_mfma_f32_16x16x32_bf16(af[i], bf[j], acc[i][j], 0, 0, 0);
        __syncthreads();
    }

    // C/D layout: col = lane&15, row = quad*4 + reg
    #pragma unroll
    for (int i = 0; i < 4; ++i) {
        #pragma unroll
        for (int reg = 0; reg < 4; ++reg) {
            int m = m0 + wm0 + i * 16 + quad * 4 + reg;
            if (m >= M) continue;
            #pragma unroll
            for (int j = 0; j < 4; ++j) {
                int n = n0 + wn0 + j * 16 + ml;
                if (n < Nout) {
                    if (Cb) Cb[(size_t)m * Nout + n] = f2bf(acc[i][j][reg]);
                    else    Cf[(size_t)m * Nout + n] = acc[i][j][reg];
                }
            }
        }
    }

    // ---- fused attention logits (Nout==256 path only): wave's 64 cols = one head ----
    if (el) {
        int head = (n0 + wn0) >> 6;
        float alv[4], arv[4];
        #pragma unroll
        for (int j = 0; j < 4; ++j) {
            alv[j] = al[head * 64 + j * 16 + ml];
            arv[j] = ar[head * 64 + j * 16 + ml];
        }
        #pragma unroll
        for (int i = 0; i < 4; ++i) {
            #pragma unroll
            for (int reg = 0; reg < 4; ++reg) {
                float sl = 0.f, sr = 0.f;
                #pragma unroll
                for (int j = 0; j < 4; ++j) {
                    float v = acc[i][j][reg];
                    sl += v * alv[j];
                    sr += v * arv[j];
                }
                #pragma unroll
                for (int off = 1; off < 16; off <<= 1) {
                    sl += __shfl_xor(sl, off);
                    sr += __shfl_xor(sr, off);
                }
                int m = m0 + wm0 + i * 16 + quad * 4 + reg;
                if (ml == 0 && m < M) {
                    el[m * 4 + head] = sl;
                    er[m * 4 + head] = sr;
                }
            }
        }
    }
}

// ================= CSR build (4-padded rows) =================
__global__ __launch_bounds__(256) void hist_k(const int* __restrict__ dst, int* __restrict__ deg) {
    int e = blockIdx.x * blockDim.x + threadIdx.x;
    if (e < NE) atomicAdd(&deg[dst[e]], 1);
}

__global__ __launch_bounds__(256) void scan1(const int* __restrict__ deg,
                                             int* __restrict__ excl,
                                             int* __restrict__ partials) {
    __shared__ int sh[256];
    int i = blockIdx.x * 256 + threadIdx.x;
    int v = (i < NN) ? ((deg[i] + 3) & ~3) : 0;
    sh[threadIdx.x] = v;
    __syncthreads();
    for (int off = 1; off < 256; off <<= 1) {
        int t = (threadIdx.x >= off) ? sh[threadIdx.x - off] : 0;
        __syncthreads();
        sh[threadIdx.x] += t;
        __syncthreads();
    }
    if (i < NN) excl[i] = sh[threadIdx.x] - v;
    if (threadIdx.x == 255) partials[blockIdx.x] = sh[255];
}

__global__ __launch_bounds__(256) void scan2(int* __restrict__ partials, int nb) {
    __shared__ int sh[256];
    int t = threadIdx.x;
    int v = (t < nb) ? partials[t] : 0;
    sh[t] = v;
    __syncthreads();
    for (int off = 1; off < 256; off <<= 1) {
        int x = (t >= off) ? sh[t - off] : 0;
        __syncthreads();
        sh[t] += x;
        __syncthreads();
    }
    if (t < nb) partials[t] = sh[t] - v;
}

__global__ __launch_bounds__(256) void scan3(const int* __restrict__ excl,
                                             const int* __restrict__ partials,
                                             int* __restrict__ rowptr) {
    int i = blockIdx.x * 256 + threadIdx.x;
    if (i < NN) rowptr[i] = excl[i] + partials[blockIdx.x];
}

// scatter: stores BYTE-SCALED src (src*512 = row byte offset in 256-ushort tables)
__global__ __launch_bounds__(256) void scatter_k(const int* __restrict__ src,
                                                 const int* __restrict__ dst,
                                                 const int* __restrict__ rowptr,
                                                 int* __restrict__ cursor,
                                                 int* __restrict__ ssrc,
                                                 int* __restrict__ sdst) {
    int e = blockIdx.x * blockDim.x + threadIdx.x;
    if (e >= NE) return;
    int d = dst[e];
    int p = atomicAdd(&cursor[d], 1);
    int pos = rowptr[d] + p;
    ssrc[pos] = src[e] << 9;
    sdst[pos] = d;
}

// ===== per-CSR-slot unnormalized weights, head-planar =====
__global__ __launch_bounds__(256) void edgew_k(const int* __restrict__ ssrc,
                                               const int* __restrict__ sdst,
                                               const float* __restrict__ el,
                                               const float* __restrict__ er,
                                               float* __restrict__ wcsr) {
    int i = blockIdx.x * blockDim.x + threadIdx.x;
    if (i >= MAXSLOT) return;
    int d = sdst[i];
    float w0 = 0.f, w1 = 0.f, w2 = 0.f, w3 = 0.f;
    if (d >= 0) {
        int su = ssrc[i];               // src*512; el row offset = src*16 = su>>5
        float4 e_l = *(const float4*)((const char*)el + (su >> 5));
        float4 e_r = *(const float4*)&er[d * 4];
        float v0 = e_l.x + e_r.x; v0 = fmaxf(v0, 0.2f * v0);
        float v1 = e_l.y + e_r.y; v1 = fmaxf(v1, 0.2f * v1);
        float v2 = e_l.z + e_r.z; v2 = fmaxf(v2, 0.2f * v2);
        float v3 = e_l.w + e_r.w; v3 = fmaxf(v3, 0.2f * v3);
        w0 = __expf(v0); w1 = __expf(v1); w2 = __expf(v2); w3 = __expf(v3);
    }
    wcsr[0 * MAXSLOT + i] = w0;
    wcsr[1 * MAXSLOT + i] = w1;
    wcsr[2 * MAXSLOT + i] = w2;
    wcsr[3 * MAXSLOT + i] = w3;
}

// ===== layers 1/2 aggregation: 1 wave/node, byte-scaled gathers, f32x2 packed acc ===
__global__ __launch_bounds__(256) void agg256(const int* __restrict__ rowptr,
                                              const int* __restrict__ deg,
                                              const int* __restrict__ ssrc,
                                              const float* __restrict__ wcsr,
                                              const unsigned short* __restrict__ feat,
                                              unsigned short* __restrict__ ybf,
                                              const float* __restrict__ wl3,
                                              const float* __restrict__ wr3,
                                              float* __restrict__ el3,
                                              float* __restrict__ er3) {
    int wid = (blockIdx.x * blockDim.x + threadIdx.x) >> 6;
    int lane = threadIdx.x & 63;
    if (wid >= NN) return;
    int n = wid;
    int start = rowptr[n];
    int cnt4 = (deg[n] + 3) & ~3;
    int head = lane >> 4;
    const float* wch = wcsr + (size_t)head * MAXSLOT;
    const char* fbase = (const char*)feat + lane * 8;
    f32x2 a01 = {0.f, 0.f}, a23 = {0.f, 0.f};
    float ssum = 0.f;
    for (int k = 0; k < cnt4; k += 4) {
        int4 sv = *(const int4*)&ssrc[start + k];
        float4 w4 = *(const float4*)&wch[start + k];
        uint2 u0 = *(const uint2*)(fbase + sv.x);
        uint2 u1 = *(const uint2*)(fbase + sv.y);
        uint2 u2 = *(const uint2*)(fbase + sv.z);
        uint2 u3 = *(const uint2*)(fbase + sv.w);
        ssum += (w4.x + w4.y) + (w4.z + w4.w);
        a01 += w4.x * bfpair(u0.x); a23 += w4.x * bfpair(u0.y);
        a01 += w4.y * bfpair(u1.x); a23 += w4.y * bfpair(u1.y);
        a01 += w4.z * bfpair(u2.x); a23 += w4.z * bfpair(u2.y);
        a01 += w4.w * bfpair(u3.x); a23 += w4.w * bfpair(u3.y);
    }
    float inv = ssum > 0.f ? 1.0f / ssum : 0.f;
    float r0 = a01.x * inv, r1 = a01.y * inv, r2 = a23.x * inv, r3 = a23.y * inv;
    r0 = r0 > 0.f ? r0 : (__expf(r0) - 1.f);
    r1 = r1 > 0.f ? r1 : (__expf(r1) - 1.f);
    r2 = r2 > 0.f ? r2 : (__expf(r2) - 1.f);
    r3 = r3 > 0.f ? r3 : (__expf(r3) - 1.f);
    ushort4 o;
    o.x = f2bf(r0); o.y = f2bf(r1); o.z = f2bf(r2); o.w = f2bf(r3);
    *(ushort4*)&ybf[(size_t)n * 256 + lane * 4] = o;

    // ---- fused layer-3 logits (layer-2 instance only) ----
    if (wl3) {
        float sl[4], sr[4];
        #pragma unroll
        for (int h = 0; h < 4; ++h) {
            float4 a4 = *(const float4*)&wl3[h * 256 + lane * 4];
            float4 b4 = *(const float4*)&wr3[h * 256 + lane * 4];
            sl[h] = r0 * a4.x + r1 * a4.y + r2 * a4.z + r3 * a4.w;
            sr[h] = r0 * b4.x + r1 * b4.y + r2 * b4.z + r3 * b4.w;
        }
        #pragma unroll
        for (int off = 32; off; off >>= 1) {
            #pragma unroll
            for (int h = 0; h < 4; ++h) {
                sl[h] += __shfl_xor(sl[h], off);
                sr[h] += __shfl_xor(sr[h], off);
            }
        }
        if (lane == 0) {
            #pragma unroll
            for (int h = 0; h < 4; ++h) {
                el3[n * 4 + h] = sl[h];
                er3[n * 4 + h] = sr[h];
            }
        }
    }
}

// ===== layer 3: aggregate x2 rows -> xagg[N][4][256] bf16, f32x2 packed acc ========
__global__ __launch_bounds__(256) void agg3(const int* __restrict__ rowptr,
                                            const int* __restrict__ deg,
                                            const int* __restrict__ ssrc,
                                            const float* __restrict__ wcsr,
                                            const unsigned short* __restrict__ x,
                                            unsigned short* __restrict__ xagg) {
    int wid = (blockIdx.x * blockDim.x + threadIdx.x) >> 6;
    int lane = threadIdx.x & 63;
    if (wid >= NN) return;
    int n = wid;
    int start = rowptr[n];
    int cnt4 = (deg[n] + 3) & ~3;
    const char* xbase = (const char*)x + lane * 8;
    f32x2 accA[4] = {}, accB[4] = {};
    float ssum[4] = {};
    for (int k = 0; k < cnt4; k += 4) {
        int4 sv = *(const int4*)&ssrc[start + k];
        float4 w0 = *(const float4*)&wcsr[0 * MAXSLOT + start + k];
        float4 w1 = *(const float4*)&wcsr[1 * MAXSLOT + start + k];
        float4 w2 = *(const float4*)&wcsr[2 * MAXSLOT + start + k];
        float4 w3 = *(const float4*)&wcsr[3 * MAXSLOT + start + k];
        uint2 u0 = *(const uint2*)(xbase + sv.x);
        uint2 u1 = *(const uint2*)(xbase + sv.y);
        uint2 u2 = *(const uint2*)(xbase + sv.z);
        uint2 u3 = *(const uint2*)(xbase + sv.w);
        ssum[0] += (w0.x + w0.y) + (w0.z + w0.w);
        ssum[1] += (w1.x + w1.y) + (w1.z + w1.w);
        ssum[2] += (w2.x + w2.y) + (w2.z + w2.w);
        ssum[3] += (w3.x + w3.y) + (w3.z + w3.w);
        f32x2 fa = bfpair(u0.x), fA = bfpair(u0.y);
        f32x2 fb = bfpair(u1.x), fB = bfpair(u1.y);
        f32x2 fc = bfpair(u2.x), fC = bfpair(u2.y);
        f32x2 fd = bfpair(u3.x), fD = bfpair(u3.y);
        accA[0] += w0.x * fa + w0.y * fb + w0.z * fc + w0.w * fd;
        accB[0] += w0.x * fA + w0.y * fB + w0.z * fC + w0.w * fD;
        accA[1] += w1.x * fa + w1.y * fb + w1.z * fc + w1.w * fd;
        accB[1] += w1.x * fA + w1.y * fB + w1.z * fC + w1.w * fD;
        accA[2] += w2.x * fa + w2.y * fb + w2.z * fc + w2.w * fd;
        accB[2] += w2.x * fA + w2.y * fB + w2.z * fC + w2.w * fD;
        accA[3] += w3.x * fa + w3.y * fb + w3.z * fc + w3.w * fd;
        accB[3] += w3.x * fA + w3.y * fB + w3.z * fC + w3.w * fD;
    }
    #pragma unroll
    for (int h = 0; h < 4; ++h) {
        float inv = ssum[h] > 0.f ? 1.f / ssum[h] : 0.f;
        ushort4 o;
        o.x = f2bf(accA[h].x * inv); o.y = f2bf(accA[h].y * inv);
        o.z = f2bf(accB[h].x * inv); o.w = f2bf(accB[h].y * inv);
        *(ushort4*)&xagg[(size_t)n * 1024 + h * 256 + lane * 4] = o;
    }
}

extern "C" void kernel_launch(void* const* d_in, const int* in_sizes, int n_in,
                              void* d_out, int out_size, void* d_ws, size_t ws_size,
                              hipStream_t stream) {
    const float* h   = (const float*)d_in[0];
    const int*   src = (const int*)d_in[1];
    const int*   dst = (const int*)d_in[2];
    const float* W1  = (const float*)d_in[3];
    const float* al1 = (const float*)d_in[4];
    const float* ar1 = (const float*)d_in[5];
    const float* W2  = (const float*)d_in[6];
    const float* al2 = (const float*)d_in[7];
    const float* ar2 = (const float*)d_in[8];
    const float* W3  = (const float*)d_in[9];
    const float* al3 = (const float*)d_in[10];
    const float* ar3 = (const float*)d_in[11];
    float* out = (float*)d_out;

    float* ws = (float*)d_ws;
    unsigned short* x_bf    = (unsigned short*)ws;
    unsigned short* h_bf    = (unsigned short*)(ws + 6400000);
    unsigned short* feat_bf = (unsigned short*)(ws + 12800000);
    unsigned short* xagg    = (unsigned short*)(ws + 6400000);  // overlays h_bf+feat_bf (dead by L3)
    float* el  = ws + 32000000;
    float* er  = ws + 32200000;
    float* wl3 = ws + 32400000;
    float* wr3 = ws + 32401024;
    unsigned short* BT1   = (unsigned short*)(ws + 32402048);
    unsigned short* BT2   = (unsigned short*)(ws + 32434816);
    unsigned short* BTcat = (unsigned short*)(ws + 32467584);
    float* wcsr = ws + 32533120;                 // 4 x 600,000 floats
    int* ibase  = (int*)(ws + 34933120);
    int* deg      = ibase;                       // 50,000
    int* cursor   = ibase + 50000;               // 50,000 (adjacent: one memset)
    int* excl     = ibase + 100000;              // 50,000
    int* partials = ibase + 150000;              // 256
    int* rowptr   = ibase + 150256;              // 50,000
    int* ssrc     = ibase + 200256;              // 600,000 (byte-scaled src)
    int* sdst     = ibase + 800256;              // 600,000

    const int NB = (NN + 255) / 256;
    const int SLOT_BLOCKS = (MAXSLOT + 255) / 256;

    // ---- CSR build (4-padded rows; pads: ssrc=0, sdst=-1) ----
    hipMemsetAsync(deg, 0, 2 * NN * sizeof(int), stream);   // deg + cursor
    hipMemsetAsync(ssrc, 0, MAXSLOT * sizeof(int), stream);
    hipMemsetAsync(sdst, 0xFF, MAXSLOT * sizeof(int), stream);
    hist_k<<<(NE + 255) / 256, 256, 0, stream>>>(dst, deg);
    scan1<<<NB, 256, 0, stream>>>(deg, excl, partials);
    scan2<<<1, 256, 0, stream>>>(partials, NB);
    scan3<<<NB, 256, 0, stream>>>(excl, partials, rowptr);
    scatter_k<<<(NE + 255) / 256, 256, 0, stream>>>(src, dst, rowptr, cursor, ssrc, sdst);

    // ---- fused casts / weight prep ----
    prep_k<<<(PREP_WV + 255) / 256, 256, 0, stream>>>(h, W1, W2, W3, al3, ar3,
                                                      h_bf, BT1, BT2, BTcat, wl3, wr3);

    dim3 g256((NN + 127) / 128, 2);
    dim3 gOut((NN + 127) / 128, 1);
    const int WAVE_BLOCKS = (NN * 64 + 255) / 256;   // one wave per node

    // ---- layer 1 ----
    gemm_bf16<<<g256, 256, 0, stream>>>(h_bf, BT1, nullptr, feat_bf, al1, ar1, el, er, NN, 256, 256);
    edgew_k<<<SLOT_BLOCKS, 256, 0, stream>>>(ssrc, sdst, el, er, wcsr);
    agg256<<<WAVE_BLOCKS, 256, 0, stream>>>(rowptr, deg, ssrc, wcsr, feat_bf, x_bf,
                                            nullptr, nullptr, nullptr, nullptr);

    // ---- layer 2 (fused layer-3 logit epilogue) ----
    gemm_bf16<<<g256, 256, 0, stream>>>(x_bf, BT2, nullptr, feat_bf, al2, ar2, el, er, NN, 256, 256);
    edgew_k<<<SLOT_BLOCKS, 256, 0, stream>>>(ssrc, sdst, el, er, wcsr);
    agg256<<<WAVE_BLOCKS, 256, 0, stream>>>(rowptr, deg, ssrc, wcsr, feat_bf, x_bf,
                                            wl3, wr3, el, er);

    // ---- layer 3 (input-side aggregation; exact reorder of reference math) ----
    edgew_k<<<SLOT_BLOCKS, 256, 0, stream>>>(ssrc, sdst, el, er, wcsr);
    agg3<<<WAVE_BLOCKS, 256, 0, stream>>>(rowptr, deg, ssrc, wcsr, x_bf, xagg);
    gemm_bf16<<<gOut, 256, 0, stream>>>(xagg, BTcat, out, nullptr, nullptr, nullptr, nullptr, nullptr, NN, NC, 1024);
}

// Round 12
// 403.329 us; speedup vs baseline: 1.1476x; 1.0246x over previous
//
#include <hip/hip_runtime.h>
#include <cstddef>

#define NN 50000
#define NE 400000
#define NH 4
#define NC 121
#define MAXSLOT 600000   // NE + 4*NN upper bound on padded CSR slots

typedef __attribute__((ext_vector_type(8))) short short8;
typedef __attribute__((ext_vector_type(4))) float f32x4;
typedef __attribute__((ext_vector_type(2))) float f32x2;

// fp32 -> bf16 round-to-nearest-even
static __device__ __forceinline__ unsigned short f2bf(float f) {
    unsigned u = __float_as_uint(f);
    u += 0x7fffu + ((u >> 16) & 1u);
    return (unsigned short)(u >> 16);
}
static __device__ __forceinline__ float bf2f(unsigned short u) {
    return __uint_as_float(((unsigned)u) << 16);
}
// dword holding 2 bf16 -> 2 floats
static __device__ __forceinline__ f32x2 bfpair(unsigned u) {
    f32x2 r;
    r.x = __uint_as_float(u << 16);
    r.y = __uint_as_float(u & 0xffff0000u);
    return r;
}
// async global->LDS, 16B per lane; LDS dest = wave-uniform base + lane*16
static __device__ __forceinline__ void load_lds16(const unsigned short* g, unsigned short* l) {
    __builtin_amdgcn_global_load_lds(
        (const __attribute__((address_space(1))) unsigned*)g,
        (__attribute__((address_space(3))) unsigned*)l, 16, 0, 0);
}

// ======== fused prep: cast_x + BT1 + BT2 + BTcat + wvec3 + dst histogram ==========
#define PREP_X    3200000            // NN*256/4 float4->ushort4 items
#define PREP_BT1  (PREP_X + 65536)
#define PREP_BT2  (PREP_BT1 + 65536)
#define PREP_CAT  (PREP_BT2 + 131072)
#define PREP_WV   (PREP_CAT + 2048)
#define PREP_END  (PREP_WV + NE)
__global__ __launch_bounds__(256) void prep_k(const float* __restrict__ h,
                                              const float* __restrict__ W1,
                                              const float* __restrict__ W2,
                                              const float* __restrict__ W3,
                                              const float* __restrict__ al3,
                                              const float* __restrict__ ar3,
                                              const int* __restrict__ dst,
                                              unsigned short* __restrict__ h_bf,
                                              unsigned short* __restrict__ BT1,
                                              unsigned short* __restrict__ BT2,
                                              unsigned short* __restrict__ BTcat,
                                              float* __restrict__ wl3,
                                              float* __restrict__ wr3,
                                              int* __restrict__ deg) {
    int i = blockIdx.x * blockDim.x + threadIdx.x;
    if (i < PREP_X) {
        float4 v = *(const float4*)&h[(size_t)i * 4];
        ushort4 o;
        o.x = f2bf(v.x); o.y = f2bf(v.y); o.z = f2bf(v.z); o.w = f2bf(v.w);
        *(ushort4*)&h_bf[(size_t)i * 4] = o;
    } else if (i < PREP_BT1) {
        int j = i - PREP_X;
        int n = j >> 8, k = j & 255;
        BT1[j] = f2bf(W1[(size_t)k * 256 + n]);
    } else if (i < PREP_BT2) {
        int j = i - PREP_BT1;
        int n = j >> 8, k = j & 255;
        BT2[j] = f2bf(W2[(size_t)k * 256 + n]);
    } else if (i < PREP_CAT) {
        int j = i - PREP_BT2;
        int c = j >> 10, kk = j & 1023;
        int hh = kk >> 8, k = kk & 255;
        float v = (c < NC) ? 0.25f * W3[(size_t)k * 484 + hh * NC + c] : 0.f;
        BTcat[j] = f2bf(v);
    } else if (i < PREP_WV) {
        int j = (i - PREP_CAT) & 1023;
        int sel = (i - PREP_CAT) >> 10;
        int hh = j >> 8, k = j & 255;
        const float* a = sel ? ar3 : al3;
        const float* wrow = W3 + (size_t)k * 484 + hh * NC;
        const float* arow = a + hh * NC;
        float s = 0.f;
        for (int d = 0; d < NC; ++d) s += wrow[d] * arow[d];
        if (sel) wr3[j] = s; else wl3[j] = s;
    } else if (i < PREP_END) {
        atomicAdd(&deg[dst[i - PREP_WV]], 1);
    }
}

// ================= MFMA GEMM, global_load_lds staging, fused logit epilogue ========
__global__ __launch_bounds__(256) void gemm_bf16(const unsigned short* __restrict__ A,
                                                 const unsigned short* __restrict__ BT,
                                                 float* __restrict__ Cf,
                                                 unsigned short* __restrict__ Cb,
                                                 const float* __restrict__ al,
                                                 const float* __restrict__ ar,
                                                 float* __restrict__ el,
                                                 float* __restrict__ er,
                                                 int M, int Nout, int K) {
    __shared__ __align__(16) unsigned short Alds[128 * 32];
    __shared__ __align__(16) unsigned short Blds[128 * 32];
    const int tid = threadIdx.x;
    const int wave = tid >> 6;
    const int lane = tid & 63;
    const int quad = lane >> 4;
    const int ml = lane & 15;
    const int m0 = blockIdx.x * 128;
    const int n0 = blockIdx.y * 128;
    const int wm0 = (wave >> 1) * 64;
    const int wn0 = (wave & 1) * 64;

    const unsigned short* Ab = A + (size_t)(m0 + wave * 16 + (lane >> 2)) * K + (lane & 3) * 8;
    const unsigned short* Bb = BT + (size_t)(n0 + wave * 16 + (lane >> 2)) * K + (lane & 3) * 8;
    unsigned short* AldsW = Alds + wave * 512;
    unsigned short* BldsW = Blds + wave * 512;

    f32x4 acc[4][4] = {};

    for (int k0 = 0; k0 < K; k0 += 32) {
        #pragma unroll
        for (int p = 0; p < 2; ++p) {
            load_lds16(Ab + (size_t)(p * 64) * K + k0, AldsW + p * 2048);
            load_lds16(Bb + (size_t)(p * 64) * K + k0, BldsW + p * 2048);
        }
        __syncthreads();

        short8 af[4], bf[4];
        #pragma unroll
        for (int i = 0; i < 4; ++i)
            af[i] = *(const short8*)&Alds[(wm0 + i * 16 + ml) * 32 + quad * 8];
        #pragma unroll
        for (int j = 0; j < 4; ++j)
            bf[j] = *(const short8*)&Blds[(wn0 + j * 16 + ml) * 32 + quad * 8];
        #pragma unroll
        for (int i = 0; i < 4; ++i)
            #pragma unroll
            for (int j = 0; j < 4; ++j)
                acc[i][j] = __builtin_amdgcn_mfma_f32_16x16x32_bf16(af[i], bf[j], acc[i][j], 0, 0, 0);
        __syncthreads();
    }

    // C/D layout: col = lane&15, row = quad*4 + reg
    #pragma unroll
    for (int i = 0; i < 4; ++i) {
        #pragma unroll
        for (int reg = 0; reg < 4; ++reg) {
            int m = m0 + wm0 + i * 16 + quad * 4 + reg;
            if (m >= M) continue;
            #pragma unroll
            for (int j = 0; j < 4; ++j) {
                int n = n0 + wn0 + j * 16 + ml;
                if (n < Nout) {
                    if (Cb) Cb[(size_t)m * Nout + n] = f2bf(acc[i][j][reg]);
                    else    Cf[(size_t)m * Nout + n] = acc[i][j][reg];
                }
            }
        }
    }

    // ---- fused attention logits (Nout==256 path only): wave's 64 cols = one head ----
    if (el) {
        int head = (n0 + wn0) >> 6;
        float alv[4], arv[4];
        #pragma unroll
        for (int j = 0; j < 4; ++j) {
            alv[j] = al[head * 64 + j * 16 + ml];
            arv[j] = ar[head * 64 + j * 16 + ml];
        }
        #pragma unroll
        for (int i = 0; i < 4; ++i) {
            #pragma unroll
            for (int reg = 0; reg < 4; ++reg) {
                float sl = 0.f, sr = 0.f;
                #pragma unroll
                for (int j = 0; j < 4; ++j) {
                    float v = acc[i][j][reg];
                    sl += v * alv[j];
                    sr += v * arv[j];
                }
                #pragma unroll
                for (int off = 1; off < 16; off <<= 1) {
                    sl += __shfl_xor(sl, off);
                    sr += __shfl_xor(sr, off);
                }
                int m = m0 + wm0 + i * 16 + quad * 4 + reg;
                if (ml == 0 && m < M) {
                    el[m * 4 + head] = sl;
                    er[m * 4 + head] = sr;
                }
            }
        }
    }
}

// ================= CSR build (4-padded rows) =================
__global__ __launch_bounds__(256) void scan1(const int* __restrict__ deg,
                                             int* __restrict__ excl,
                                             int* __restrict__ partials) {
    __shared__ int sh[256];
    int i = blockIdx.x * 256 + threadIdx.x;
    int v = (i < NN) ? ((deg[i] + 3) & ~3) : 0;
    sh[threadIdx.x] = v;
    __syncthreads();
    for (int off = 1; off < 256; off <<= 1) {
        int t = (threadIdx.x >= off) ? sh[threadIdx.x - off] : 0;
        __syncthreads();
        sh[threadIdx.x] += t;
        __syncthreads();
    }
    if (i < NN) excl[i] = sh[threadIdx.x] - v;
    if (threadIdx.x == 255) partials[blockIdx.x] = sh[255];
}

__global__ __launch_bounds__(256) void scan2(int* __restrict__ partials, int nb) {
    __shared__ int sh[256];
    int t = threadIdx.x;
    int v = (t < nb) ? partials[t] : 0;
    sh[t] = v;
    __syncthreads();
    for (int off = 1; off < 256; off <<= 1) {
        int x = (t >= off) ? sh[t - off] : 0;
        __syncthreads();
        sh[t] += x;
        __syncthreads();
    }
    if (t < nb) partials[t] = sh[t] - v;
}

__global__ __launch_bounds__(256) void scan3(const int* __restrict__ excl,
                                             const int* __restrict__ partials,
                                             int* __restrict__ rowptr) {
    int i = blockIdx.x * 256 + threadIdx.x;
    if (i < NN) rowptr[i] = excl[i] + partials[blockIdx.x];
}

// scatter: stores BYTE-SCALED src (src*512 = row byte offset in 256-ushort tables)
__global__ __launch_bounds__(256) void scatter_k(const int* __restrict__ src,
                                                 const int* __restrict__ dst,
                                                 const int* __restrict__ rowptr,
                                                 int* __restrict__ cursor,
                                                 int* __restrict__ ssrc,
                                                 int* __restrict__ sdst) {
    int e = blockIdx.x * blockDim.x + threadIdx.x;
    if (e >= NE) return;
    int d = dst[e];
    int p = atomicAdd(&cursor[d], 1);
    int pos = rowptr[d] + p;
    ssrc[pos] = src[e] << 9;
    sdst[pos] = d;
}

// ===== per-CSR-slot unnormalized weights, head-planar (layer 3 only) =====
__global__ __launch_bounds__(256) void edgew_k(const int* __restrict__ ssrc,
                                               const int* __restrict__ sdst,
                                               const float* __restrict__ el,
                                               const float* __restrict__ er,
                                               float* __restrict__ wcsr) {
    int i = blockIdx.x * blockDim.x + threadIdx.x;
    if (i >= MAXSLOT) return;
    int d = sdst[i];
    float w0 = 0.f, w1 = 0.f, w2 = 0.f, w3 = 0.f;
    if (d >= 0) {
        int su = ssrc[i];               // src*512; el row offset = src*16 = su>>5
        float4 e_l = *(const float4*)((const char*)el + (su >> 5));
        float4 e_r = *(const float4*)&er[d * 4];
        float v0 = e_l.x + e_r.x; v0 = fmaxf(v0, 0.2f * v0);
        float v1 = e_l.y + e_r.y; v1 = fmaxf(v1, 0.2f * v1);
        float v2 = e_l.z + e_r.z; v2 = fmaxf(v2, 0.2f * v2);
        float v3 = e_l.w + e_r.w; v3 = fmaxf(v3, 0.2f * v3);
        w0 = __expf(v0); w1 = __expf(v1); w2 = __expf(v2); w3 = __expf(v3);
    }
    wcsr[0 * MAXSLOT + i] = w0;
    wcsr[1 * MAXSLOT + i] = w1;
    wcsr[2 * MAXSLOT + i] = w2;
    wcsr[3 * MAXSLOT + i] = w3;
}

// ===== layers 1/2 aggregation: fused edge weights (leaky+exp inline), 1 wave/node ===
// el3/er3 (fused layer-3 logit outputs) MUST be disjoint from el/er (read here)!
__global__ __launch_bounds__(256) void agg256(const int* __restrict__ rowptr,
                                              const int* __restrict__ deg,
                                              const int* __restrict__ ssrc,
                                              const float* __restrict__ el,
                                              const float* __restrict__ er,
                                              const unsigned short* __restrict__ feat,
                                              unsigned short* __restrict__ ybf,
                                              const float* __restrict__ wl3,
                                              const float* __restrict__ wr3,
                                              float* __restrict__ el3,
                                              float* __restrict__ er3) {
    int wid = (blockIdx.x * blockDim.x + threadIdx.x) >> 6;
    int lane = threadIdx.x & 63;
    if (wid >= NN) return;
    int n = wid;
    int start = rowptr[n];
    int cnt = deg[n];
    int cnt4 = (cnt + 3) & ~3;
    int head = lane >> 4;
    float ern = er[n * 4 + head];
    const char* elb = (const char*)el + head * 4;   // + (src*16) per edge
    const char* fbase = (const char*)feat + lane * 8;
    f32x2 a01 = {0.f, 0.f}, a23 = {0.f, 0.f};
    float ssum = 0.f;
    for (int k = 0; k < cnt4; k += 4) {
        int4 sv = *(const int4*)&ssrc[start + k];   // wave-uniform -> scalar loads
        float e0 = *(const float*)(elb + (sv.x >> 5));
        float e1 = *(const float*)(elb + (sv.y >> 5));
        float e2 = *(const float*)(elb + (sv.z >> 5));
        float e3 = *(const float*)(elb + (sv.w >> 5));
        float v0 = e0 + ern; v0 = fmaxf(v0, 0.2f * v0);
        float v1 = e1 + ern; v1 = fmaxf(v1, 0.2f * v1);
        float v2 = e2 + ern; v2 = fmaxf(v2, 0.2f * v2);
        float v3 = e3 + ern; v3 = fmaxf(v3, 0.2f * v3);
        float w0 = (k + 0 < cnt) ? __expf(v0) : 0.f;
        float w1 = (k + 1 < cnt) ? __expf(v1) : 0.f;
        float w2 = (k + 2 < cnt) ? __expf(v2) : 0.f;
        float w3 = (k + 3 < cnt) ? __expf(v3) : 0.f;
        uint2 u0 = *(const uint2*)(fbase + sv.x);
        uint2 u1 = *(const uint2*)(fbase + sv.y);
        uint2 u2 = *(const uint2*)(fbase + sv.z);
        uint2 u3 = *(const uint2*)(fbase + sv.w);
        ssum += (w0 + w1) + (w2 + w3);
        a01 += w0 * bfpair(u0.x); a23 += w0 * bfpair(u0.y);
        a01 += w1 * bfpair(u1.x); a23 += w1 * bfpair(u1.y);
        a01 += w2 * bfpair(u2.x); a23 += w2 * bfpair(u2.y);
        a01 += w3 * bfpair(u3.x); a23 += w3 * bfpair(u3.y);
    }
    float inv = ssum > 0.f ? 1.0f / ssum : 0.f;
    float r0 = a01.x * inv, r1 = a01.y * inv, r2 = a23.x * inv, r3 = a23.y * inv;
    r0 = r0 > 0.f ? r0 : (__expf(r0) - 1.f);
    r1 = r1 > 0.f ? r1 : (__expf(r1) - 1.f);
    r2 = r2 > 0.f ? r2 : (__expf(r2) - 1.f);
    r3 = r3 > 0.f ? r3 : (__expf(r3) - 1.f);
    ushort4 o;
    o.x = f2bf(r0); o.y = f2bf(r1); o.z = f2bf(r2); o.w = f2bf(r3);
    *(ushort4*)&ybf[(size_t)n * 256 + lane * 4] = o;

    // ---- fused layer-3 logits (layer-2 instance only; writes DISJOINT el3/er3) ----
    if (wl3) {
        float sl[4], sr[4];
        #pragma unroll
        for (int h = 0; h < 4; ++h) {
            float4 a4 = *(const float4*)&wl3[h * 256 + lane * 4];
            float4 b4 = *(const float4*)&wr3[h * 256 + lane * 4];
            sl[h] = r0 * a4.x + r1 * a4.y + r2 * a4.z + r3 * a4.w;
            sr[h] = r0 * b4.x + r1 * b4.y + r2 * b4.z + r3 * b4.w;
        }
        #pragma unroll
        for (int off = 32; off; off >>= 1) {
            #pragma unroll
            for (int h = 0; h < 4; ++h) {
                sl[h] += __shfl_xor(sl[h], off);
                sr[h] += __shfl_xor(sr[h], off);
            }
        }
        if (lane == 0) {
            #pragma unroll
            for (int h = 0; h < 4; ++h) {
                el3[n * 4 + h] = sl[h];
                er3[n * 4 + h] = sr[h];
            }
        }
    }
}

// ===== layer 3: aggregate x2 rows -> xagg[N][4][256] bf16, f32x2 packed acc ========
__global__ __launch_bounds__(256) void agg3(const int* __restrict__ rowptr,
                                            const int* __restrict__ deg,
                                            const int* __restrict__ ssrc,
                                            const float* __restrict__ wcsr,
                                            const unsigned short* __restrict__ x,
                                            unsigned short* __restrict__ xagg) {
    int wid = (blockIdx.x * blockDim.x + threadIdx.x) >> 6;
    int lane = threadIdx.x & 63;
    if (wid >= NN) return;
    int n = wid;
    int start = rowptr[n];
    int cnt4 = (deg[n] + 3) & ~3;
    const char* xbase = (const char*)x + lane * 8;
    f32x2 accA[4] = {}, accB[4] = {};
    float ssum[4] = {};
    for (int k = 0; k < cnt4; k += 4) {
        int4 sv = *(const int4*)&ssrc[start + k];
        float4 w0 = *(const float4*)&wcsr[0 * MAXSLOT + start + k];
        float4 w1 = *(const float4*)&wcsr[1 * MAXSLOT + start + k];
        float4 w2 = *(const float4*)&wcsr[2 * MAXSLOT + start + k];
        float4 w3 = *(const float4*)&wcsr[3 * MAXSLOT + start + k];
        uint2 u0 = *(const uint2*)(xbase + sv.x);
        uint2 u1 = *(const uint2*)(xbase + sv.y);
        uint2 u2 = *(const uint2*)(xbase + sv.z);
        uint2 u3 = *(const uint2*)(xbase + sv.w);
        ssum[0] += (w0.x + w0.y) + (w0.z + w0.w);
        ssum[1] += (w1.x + w1.y) + (w1.z + w1.w);
        ssum[2] += (w2.x + w2.y) + (w2.z + w2.w);
        ssum[3] += (w3.x + w3.y) + (w3.z + w3.w);
        f32x2 fa = bfpair(u0.x), fA = bfpair(u0.y);
        f32x2 fb = bfpair(u1.x), fB = bfpair(u1.y);
        f32x2 fc = bfpair(u2.x), fC = bfpair(u2.y);
        f32x2 fd = bfpair(u3.x), fD = bfpair(u3.y);
        accA[0] += w0.x * fa + w0.y * fb + w0.z * fc + w0.w * fd;
        accB[0] += w0.x * fA + w0.y * fB + w0.z * fC + w0.w * fD;
        accA[1] += w1.x * fa + w1.y * fb + w1.z * fc + w1.w * fd;
        accB[1] += w1.x * fA + w1.y * fB + w1.z * fC + w1.w * fD;
        accA[2] += w2.x * fa + w2.y * fb + w2.z * fc + w2.w * fd;
        accB[2] += w2.x * fA + w2.y * fB + w2.z * fC + w2.w * fD;
        accA[3] += w3.x * fa + w3.y * fb + w3.z * fc + w3.w * fd;
        accB[3] += w3.x * fA + w3.y * fB + w3.z * fC + w3.w * fD;
    }
    #pragma unroll
    for (int h = 0; h < 4; ++h) {
        float inv = ssum[h] > 0.f ? 1.f / ssum[h] : 0.f;
        ushort4 o;
        o.x = f2bf(accA[h].x * inv); o.y = f2bf(accA[h].y * inv);
        o.z = f2bf(accB[h].x * inv); o.w = f2bf(accB[h].y * inv);
        *(ushort4*)&xagg[(size_t)n * 1024 + h * 256 + lane * 4] = o;
    }
}

extern "C" void kernel_launch(void* const* d_in, const int* in_sizes, int n_in,
                              void* d_out, int out_size, void* d_ws, size_t ws_size,
                              hipStream_t stream) {
    const float* h   = (const float*)d_in[0];
    const int*   src = (const int*)d_in[1];
    const int*   dst = (const int*)d_in[2];
    const float* W1  = (const float*)d_in[3];
    const float* al1 = (const float*)d_in[4];
    const float* ar1 = (const float*)d_in[5];
    const float* W2  = (const float*)d_in[6];
    const float* al2 = (const float*)d_in[7];
    const float* ar2 = (const float*)d_in[8];
    const float* W3  = (const float*)d_in[9];
    const float* al3 = (const float*)d_in[10];
    const float* ar3 = (const float*)d_in[11];
    float* out = (float*)d_out;

    float* ws = (float*)d_ws;
    unsigned short* x_bf    = (unsigned short*)ws;
    unsigned short* h_bf    = (unsigned short*)(ws + 6400000);
    unsigned short* feat_bf = (unsigned short*)(ws + 12800000);
    unsigned short* xagg    = (unsigned short*)(ws + 6400000);  // overlays h_bf+feat_bf (dead by L3)
    float* el  = ws + 32000000;
    float* er  = ws + 32200000;
    float* wl3 = ws + 32400000;
    float* wr3 = ws + 32401024;
    unsigned short* BT1   = (unsigned short*)(ws + 32402048);
    unsigned short* BT2   = (unsigned short*)(ws + 32434816);
    unsigned short* BTcat = (unsigned short*)(ws + 32467584);
    float* wcsr = ws + 32533120;                 // 4 x 600,000 floats (layer 3 only)
    int* ibase  = (int*)(ws + 34933120);
    int* deg      = ibase;                       // 50,000
    int* cursor   = ibase + 50000;               // 50,000 (adjacent: one memset)
    int* excl     = ibase + 100000;              // 50,000
    int* partials = ibase + 150000;              // 256
    int* rowptr   = ibase + 150256;              // 50,000
    int* ssrc     = ibase + 200256;              // 600,000 (byte-scaled src)
    int* sdst     = ibase + 800256;              // 600,000
    float* el2 = ws + 36333376;                  // 200,000 (layer-3 logits, DISJOINT from el)
    float* er2 = ws + 36533376;                  // 200,000

    const int NB = (NN + 255) / 256;
    const int SLOT_BLOCKS = (MAXSLOT + 255) / 256;

    // ---- memsets (pads: ssrc=0, sdst=-1) ----
    hipMemsetAsync(deg, 0, 2 * NN * sizeof(int), stream);   // deg + cursor
    hipMemsetAsync(ssrc, 0, MAXSLOT * sizeof(int), stream);
    hipMemsetAsync(sdst, 0xFF, MAXSLOT * sizeof(int), stream);

    // ---- fused prep: casts + weight prep + dst histogram ----
    prep_k<<<(PREP_END + 255) / 256, 256, 0, stream>>>(h, W1, W2, W3, al3, ar3, dst,
                                                       h_bf, BT1, BT2, BTcat, wl3, wr3, deg);

    // ---- CSR build ----
    scan1<<<NB, 256, 0, stream>>>(deg, excl, partials);
    scan2<<<1, 256, 0, stream>>>(partials, NB);
    scan3<<<NB, 256, 0, stream>>>(excl, partials, rowptr);
    scatter_k<<<(NE + 255) / 256, 256, 0, stream>>>(src, dst, rowptr, cursor, ssrc, sdst);

    dim3 g256((NN + 127) / 128, 2);
    dim3 gOut((NN + 127) / 128, 1);
    const int WAVE_BLOCKS = (NN * 64 + 255) / 256;   // one wave per node

    // ---- layer 1 (agg computes edge weights inline from el/er) ----
    gemm_bf16<<<g256, 256, 0, stream>>>(h_bf, BT1, nullptr, feat_bf, al1, ar1, el, er, NN, 256, 256);
    agg256<<<WAVE_BLOCKS, 256, 0, stream>>>(rowptr, deg, ssrc, el, er, feat_bf, x_bf,
                                            nullptr, nullptr, nullptr, nullptr);

    // ---- layer 2 (fused layer-3 logit epilogue -> el2/er2, disjoint) ----
    gemm_bf16<<<g256, 256, 0, stream>>>(x_bf, BT2, nullptr, feat_bf, al2, ar2, el, er, NN, 256, 256);
    agg256<<<WAVE_BLOCKS, 256, 0, stream>>>(rowptr, deg, ssrc, el, er, feat_bf, x_bf,
                                            wl3, wr3, el2, er2);

    // ---- layer 3 (input-side aggregation; exact reorder of reference math) ----
    edgew_k<<<SLOT_BLOCKS, 256, 0, stream>>>(ssrc, sdst, el2, er2, wcsr);
    agg3<<<WAVE_BLOCKS, 256, 0, stream>>>(rowptr, deg, ssrc, wcsr, x_bf, xagg);
    gemm_bf16<<<gOut, 256, 0, stream>>>(xagg, BTcat, out, nullptr, nullptr, nullptr, nullptr, nullptr, NN, NC, 1024);
}